// Round 3
// baseline (516.571 us; speedup 1.0000x reference)
//
#include <hip/hip_runtime.h>
#include <hip/hip_bf16.h>
#include <math.h>

typedef __attribute__((ext_vector_type(8))) short short8;
typedef __attribute__((ext_vector_type(4))) float floatx4;

#define KEXP (-9.210340371976184f / 1024.0f)   // -ln(10000)/1024

__device__ inline unsigned f2bf1(float f) {
    union { float f; unsigned u; } v; v.f = f;
    return (v.u + 0x8000u) >> 16;   // round-half-up to bf16
}

__device__ inline short8 pack8(float4 a, float4 b) {
    short8 r;
    r[0] = (short)f2bf1(a.x); r[1] = (short)f2bf1(a.y);
    r[2] = (short)f2bf1(a.z); r[3] = (short)f2bf1(a.w);
    r[4] = (short)f2bf1(b.x); r[5] = (short)f2bf1(b.y);
    r[6] = (short)f2bf1(b.z); r[7] = (short)f2bf1(b.w);
    return r;
}

// -------- segment-average: x (16,128,512) -> xcf (32, 2048), m = b*16 + a ----
__global__ __launch_bounds__(128) void avg_k(const float* __restrict__ x,
                                             float* __restrict__ xcf) {
    int blk = blockIdx.x;            // a*128 + b
    int a = blk >> 7, b = blk & 127;
    int t = threadIdx.x;
    const float4 v = *(const float4*)(x + ((size_t)a * 128 + b) * 512 + t * 4);
    float s = v.x + v.y + v.z + v.w;
    s += __shfl_xor(s, 1);
    s += __shfl_xor(s, 2);
    if ((t & 3) == 0) {
        int seg = t >> 2;            // 0..31
        xcf[seg * 2048 + b * 16 + a] = s * (1.0f / 16.0f);
    }
}

// -------- thin GEMM: slab[chunk][32][N] = Xe[32,Kchunk] @ W[N,Kchunk]^T ------
// XMODE 0: Xe = X raw; 1: Xe = LN(X) via (psum,psq) stats; 2: Xe = LN(X)+X
template<int KCHUNK, int XMODE>
__global__ __launch_bounds__(256) void gemm_k(const float* __restrict__ X,
                                              const float* __restrict__ W,
                                              float* __restrict__ slab,
                                              const float* __restrict__ g,
                                              const float* __restrict__ bl,
                                              const float* __restrict__ psum,
                                              const float* __restrict__ psq,
                                              int N, int K) {
    constexpr int PITCH = KCHUNK + 8;
    __shared__ unsigned short Xs[32 * PITCH];
    __shared__ float ldsM[32], ldsR[32];
    const int tid = threadIdx.x;
    const int bx = blockIdx.x, by = blockIdx.y;
    const int kb0 = by * KCHUNK;

    constexpr int PER = (32 * (KCHUNK / 4)) / 256;   // float4s per thread
    float4 xv[PER], gv[PER], bv[PER];
    int rows[PER], c4s[PER];
#pragma unroll
    for (int p = 0; p < PER; p++) {
        int f = tid + 256 * p;
        int row = f / (KCHUNK / 4), c4 = f % (KCHUNK / 4);
        rows[p] = row; c4s[p] = c4;
        xv[p] = *(const float4*)(X + (size_t)row * K + kb0 + c4 * 4);
        if (XMODE != 0) {
            gv[p] = *(const float4*)(g + kb0 + c4 * 4);
            bv[p] = *(const float4*)(bl + kb0 + c4 * 4);
        }
    }
    if (XMODE != 0 && tid < 32) {
        float s = 0.f, q = 0.f;
#pragma unroll
        for (int j = 0; j < 8; j++) { s += psum[tid * 8 + j]; q += psq[tid * 8 + j]; }
        float mean = s * (1.0f / 2048.0f);
        float var = q * (1.0f / 2048.0f) - mean * mean;
        ldsM[tid] = mean;
        ldsR[tid] = rsqrtf(var + 1e-5f);
    }
    __syncthreads();
#pragma unroll
    for (int p = 0; p < PER; p++) {
        float4 v = xv[p];
        if (XMODE != 0) {
            float m = ldsM[rows[p]], r = ldsR[rows[p]];
            float4 o;
            o.x = (v.x - m) * r * gv[p].x + bv[p].x;
            o.y = (v.y - m) * r * gv[p].y + bv[p].y;
            o.z = (v.z - m) * r * gv[p].z + bv[p].z;
            o.w = (v.w - m) * r * gv[p].w + bv[p].w;
            if (XMODE == 2) { o.x += v.x; o.y += v.y; o.z += v.z; o.w += v.w; }
            v = o;
        }
        ushort4 pk;
        pk.x = (unsigned short)f2bf1(v.x);
        pk.y = (unsigned short)f2bf1(v.y);
        pk.z = (unsigned short)f2bf1(v.z);
        pk.w = (unsigned short)f2bf1(v.w);
        *(ushort4*)&Xs[rows[p] * PITCH + c4s[p] * 4] = pk;
    }
    __syncthreads();

    const int w = tid >> 6, lane = tid & 63;
    const int q = lane >> 4, r16 = lane & 15;
    const int nb = bx * 128 + w * 32;
    floatx4 acc[2][2] = {};
    const float* wp0 = W + (size_t)(nb + r16) * K + kb0 + q * 8;
    const float* wp1 = W + (size_t)(nb + 16 + r16) * K + kb0 + q * 8;

#pragma unroll
    for (int kk = 0; kk < KCHUNK; kk += 32) {
        short8 a0 = *(const short8*)&Xs[r16 * PITCH + kk + q * 8];
        short8 a1 = *(const short8*)&Xs[(16 + r16) * PITCH + kk + q * 8];
        {
            float4 u0 = *(const float4*)(wp0 + kk);
            float4 u1 = *(const float4*)(wp0 + kk + 4);
            short8 bf = pack8(u0, u1);
            acc[0][0] = __builtin_amdgcn_mfma_f32_16x16x32_bf16(a0, bf, acc[0][0], 0, 0, 0);
            acc[1][0] = __builtin_amdgcn_mfma_f32_16x16x32_bf16(a1, bf, acc[1][0], 0, 0, 0);
        }
        {
            float4 u0 = *(const float4*)(wp1 + kk);
            float4 u1 = *(const float4*)(wp1 + kk + 4);
            short8 bf = pack8(u0, u1);
            acc[0][1] = __builtin_amdgcn_mfma_f32_16x16x32_bf16(a0, bf, acc[0][1], 0, 0, 0);
            acc[1][1] = __builtin_amdgcn_mfma_f32_16x16x32_bf16(a1, bf, acc[1][1], 0, 0, 0);
        }
    }

    float* outp = slab + (size_t)by * 32 * N;
#pragma unroll
    for (int mt = 0; mt < 2; mt++)
#pragma unroll
        for (int nt = 0; nt < 2; nt++)
#pragma unroll
            for (int e = 0; e < 4; e++) {
                int i = mt * 16 + q * 4 + e;          // C/D: row = quad*4 + reg
                int n = nb + nt * 16 + r16;           //      col = lane&15
                outp[(size_t)i * N + n] = acc[mt][nt][e];
            }
}

// -------- reduce slab (NCH chunks of 32x2048) -> dst + LN stat partials ------
// MODE 0: +posbias; MODE 1: += dst (in place); MODE 2: +bias[col]
template<int NCH, int MODE>
__global__ __launch_bounds__(256) void red_k(const float* __restrict__ slab,
                                             const float* __restrict__ bias,
                                             float* __restrict__ dst,
                                             float* __restrict__ psum,
                                             float* __restrict__ psq) {
    __shared__ float rs[4], rq[4];
    const int b = blockIdx.x, t = threadIdx.x;
    const int row = b >> 3, cg = b & 7;
    const int col = cg * 256 + t;
    const size_t off = (size_t)row * 2048 + col;
    float v = 0.f;
#pragma unroll
    for (int c = 0; c < NCH; c++) v += slab[(size_t)c * 65536 + off];
    if (MODE == 0) {
        int ne = col & ~1;
        float ang = (float)row * __expf((float)ne * KEXP);
        v += (col & 1) ? cosf(ang) : sinf(ang);
    } else if (MODE == 1) {
        v += dst[off];
    } else {
        v += bias[col];
    }
    dst[off] = v;
    float s = v, q = v * v;
    for (int o = 32; o; o >>= 1) { s += __shfl_down(s, o); q += __shfl_down(q, o); }
    if ((t & 63) == 0) { rs[t >> 6] = s; rq[t >> 6] = q; }
    __syncthreads();
    if (t == 0) {
        psum[row * 8 + cg] = rs[0] + rs[1] + rs[2] + rs[3];
        psq[row * 8 + cg]  = rq[0] + rq[1] + rq[2] + rq[3];
    }
}

// -------- reduce(V-gemm, 32 chunks) + inclusive cumsum over rows -> Vc -------
__global__ __launch_bounds__(256) void rVcum_k(const float* __restrict__ slab,
                                               float* __restrict__ Vc) {
    __shared__ float lds[256];       // 32 rows x 8 cols
    const int cgBase = blockIdx.x * 8;
    const int t = threadIdx.x;
    const int row = t >> 3, c = t & 7;
    const size_t off = (size_t)row * 2048 + cgBase + c;
    float v = 0.f;
#pragma unroll
    for (int ch = 0; ch < 32; ch++) v += slab[(size_t)ch * 65536 + off];
    lds[row * 8 + c] = v;
    __syncthreads();
    if (t < 8) {
        float run = 0.f;
#pragma unroll
        for (int i = 0; i < 32; i++) {
            run += lds[i * 8 + t];
            Vc[(size_t)i * 2048 + cgBase + t] = run;
        }
    }
}

// -------- reduce(fc1-gemm, 16 chunks of 32x8192) + bias + gelu -> Hb ---------
__global__ __launch_bounds__(256) void rFC1_k(const float* __restrict__ slab,
                                              const float* __restrict__ bias,
                                              float* __restrict__ Hb) {
    const int b = blockIdx.x, t = threadIdx.x;
    const int row = b >> 3, cg = b & 7;
    const int c4 = cg * 256 + t;
    const size_t off = (size_t)row * 8192 + c4 * 4;
    float4 v; v.x = 0.f; v.y = 0.f; v.z = 0.f; v.w = 0.f;
#pragma unroll
    for (int c = 0; c < 16; c++) {
        const float4 u = *(const float4*)(slab + (size_t)c * 262144 + off);
        v.x += u.x; v.y += u.y; v.z += u.z; v.w += u.w;
    }
    const float4 bb = *(const float4*)(bias + c4 * 4);
    v.x += bb.x; v.y += bb.y; v.z += bb.z; v.w += bb.w;
    v.x = 0.5f * v.x * (1.0f + erff(v.x * 0.70710678118654752f));
    v.y = 0.5f * v.y * (1.0f + erff(v.y * 0.70710678118654752f));
    v.z = 0.5f * v.z * (1.0f + erff(v.z * 0.70710678118654752f));
    v.w = 0.5f * v.w * (1.0f + erff(v.w * 0.70710678118654752f));
    *(float4*)(Hb + off) = v;
}

extern "C" void kernel_launch(void* const* d_in, const int* in_sizes, int n_in,
                              void* d_out, int out_size, void* d_ws, size_t ws_size,
                              hipStream_t stream) {
    const float* x      = (const float*)d_in[0];
    const float* weight = (const float*)d_in[1];
    // d_in[2] = Wq, d_in[3] = Wk: dead (softmax over a scalar == 1)
    const float* Wv     = (const float*)d_in[4];
    const float* Wo     = (const float*)d_in[5];
    const float* ln1g   = (const float*)d_in[6];
    const float* ln1b   = (const float*)d_in[7];
    const float* ln2g   = (const float*)d_in[8];
    const float* ln2b   = (const float*)d_in[9];
    const float* fc1w   = (const float*)d_in[10];
    const float* fc1b   = (const float*)d_in[11];
    const float* fc2w   = (const float*)d_in[12];
    const float* fc2b   = (const float*)d_in[13];
    float* ws   = (float*)d_ws;
    float* xcf  = ws;                  // 32*2048
    float* S    = ws + 65536;          // 32*2048
    float* Vc   = ws + 131072;         // 32*2048
    float* Hb   = ws + 196608;         // 32*8192
    float* psum = ws + 458752;         // 32*8
    float* psq  = ws + 459008;         // 32*8
    float* slab = ws + 460800;         // up to 64 * 32*2048 = 16 MB
    float* out  = (float*)d_out;

    avg_k<<<2048, 128, 0, stream>>>(x, xcf);

    gemm_k<64, 0><<<dim3(16, 32), 256, 0, stream>>>(xcf, weight, slab,
        nullptr, nullptr, nullptr, nullptr, 2048, 2048);
    red_k<32, 0><<<256, 256, 0, stream>>>(slab, nullptr, S, psum, psq);

    for (int a = 0; a < 3; a++) {
        // V = LN1(S) @ Wv^T   (LN fused into staging via stats)
        gemm_k<64, 1><<<dim3(16, 32), 256, 0, stream>>>(S, Wv + (size_t)a * 4194304,
            slab, ln1g, ln1b, psum, psq, 2048, 2048);
        rVcum_k<<<256, 256, 0, stream>>>(slab, Vc);
        // O = Vc @ Wo^T ; Sn = O + S (red MODE 1), stats of Sn for LN2
        gemm_k<64, 0><<<dim3(16, 32), 256, 0, stream>>>(Vc, Wo + (size_t)a * 4194304,
            slab, nullptr, nullptr, nullptr, nullptr, 2048, 2048);
        red_k<32, 1><<<256, 256, 0, stream>>>(slab, nullptr, S, psum, psq);
        // H = (LN2(Sn)+Sn) @ fc1^T ; gelu(+bias)
        gemm_k<128, 2><<<dim3(64, 16), 256, 0, stream>>>(S, fc1w, slab,
            ln2g, ln2b, psum, psq, 8192, 2048);
        rFC1_k<<<256, 256, 0, stream>>>(slab, fc1b, Hb);
        // Snew = Hb @ fc2^T + fc2_b ; stats for next layer's LN1
        gemm_k<128, 0><<<dim3(16, 64), 256, 0, stream>>>(Hb, fc2w, slab,
            nullptr, nullptr, nullptr, nullptr, 2048, 8192);
        red_k<64, 2><<<256, 256, 0, stream>>>(slab, fc2b, (a == 2) ? out : S, psum, psq);
    }
}